// Round 1
// baseline (689.227 us; speedup 1.0000x reference)
//
#include <hip/hip_runtime.h>

// ---------------------------------------------------------------------------
// QKGainAttention on MI355X (gfx950), round 1.
// Pipeline: cast(x,w)->bf16 | QKV GEMM (mfma 16x16x32 bf16, m97 structure) |
// l2norm q,k (folds qk_gain^2*log2e/sqrt(HD) into q) | flash attention
// (64q blocks, online softmax, exp2 path) | proj GEMM -> fp32 out.
// Weights int6 are EXACT in bf16; per-row scale applied in fp32 epilogue.
// Workspace layout (bytes):
//   [0,16M)        x_bf16        4096x2048
//   [16M,41.9M)    attn_w bf16   6144x2048
//   [41.9M,50.3M)  proj_w bf16   2048x2048
//   [50.3M,100.6M) qkv bf16      4096x6144
//   [100.6M,117.4M) y bf16       4096x2048
// ---------------------------------------------------------------------------

#define DEVINL __device__ __forceinline__

typedef unsigned short u16;
typedef __bf16 bf16x8 __attribute__((ext_vector_type(8)));
typedef float  f32x4  __attribute__((ext_vector_type(4)));
typedef short  short8 __attribute__((ext_vector_type(8)));
typedef u16    u16x4  __attribute__((ext_vector_type(4)));

static constexpr int T_  = 2048;
static constexpr int C_  = 2048;
static constexpr int TC3 = 6144;   // 3*C

DEVINL u16 f2bf(float f) {
  union { float f; unsigned u; } v; v.f = f;
  unsigned r = v.u + 0x7FFFu + ((v.u >> 16) & 1u);   // RNE
  return (u16)(r >> 16);
}
DEVINL float bf2f(u16 s) {
  union { unsigned u; float f; } v; v.u = ((unsigned)s) << 16;
  return v.f;
}
DEVINL bf16x8 ld8(const u16* p) {
  return __builtin_bit_cast(bf16x8, *(const short8*)p);
}
DEVINL f32x4 mfma16(bf16x8 a, bf16x8 b, f32x4 c) {
  return __builtin_amdgcn_mfma_f32_16x16x32_bf16(a, b, c, 0, 0, 0);
}
DEVINL void async_cp16(const u16* gp, u16* lp) {
  __builtin_amdgcn_global_load_lds(
      (const __attribute__((address_space(1))) void*)gp,
      (__attribute__((address_space(3))) void*)lp, 16, 0, 0);
}

// ---------------- dtype casts ----------------
__global__ __launch_bounds__(256) void k_cast_x(const float* __restrict__ in,
                                                u16* __restrict__ out) {
  long i = (long)(blockIdx.x * 256 + threadIdx.x) * 4;
  float4 v = *(const float4*)(in + i);
  u16x4 o; o.x = f2bf(v.x); o.y = f2bf(v.y); o.z = f2bf(v.z); o.w = f2bf(v.w);
  *(u16x4*)(out + i) = o;
}
__global__ __launch_bounds__(256) void k_cast_w(const int* __restrict__ in,
                                                u16* __restrict__ out) {
  long i = (long)(blockIdx.x * 256 + threadIdx.x) * 4;
  int4 v = *(const int4*)(in + i);
  u16x4 o; o.x = f2bf((float)v.x); o.y = f2bf((float)v.y);
  o.z = f2bf((float)v.z); o.w = f2bf((float)v.w);
  *(u16x4*)(out + i) = o;
}

// ---------------- GEMM: C[m,n] = (sum_k A[m,k]*Bt[n,k]) * scale[n] ----------
// m97 structure: 128x128 tile, BK=32, 4 waves (2x2), 4x4 16x16 blocks/wave.
template<bool OUT_BF16>
__global__ __launch_bounds__(256) void k_gemm_bt(
    const u16* __restrict__ A, const u16* __restrict__ Bt,
    const float* __restrict__ scale, void* __restrict__ Cv,
    int N, long K) {
  __shared__ u16 As[128 * 32];
  __shared__ u16 Bs[128 * 32];
  const int tid  = threadIdx.x;
  const int wave = tid >> 6;
  const int lane = tid & 63;
  const int l15  = lane & 15;
  const int quad = lane >> 4;
  const int wm = (wave & 1) * 64;
  const int wn = (wave >> 1) * 64;
  const long bm = (long)blockIdx.y * 128;
  const long bn = (long)blockIdx.x * 128;

  f32x4 acc[4][4] = {};

  const int srow = lane >> 2;          // row within 16-row chunk
  const int scol = (lane & 3) * 8;     // elem col within BK=32

  for (long k0 = 0; k0 < K; k0 += 32) {
#pragma unroll
    for (int i = 0; i < 2; ++i) {
      const int j = wave * 2 + i;              // chunk 0..7 (1024B each)
      const int row = j * 16 + srow;
      async_cp16(A  + (bm + row) * K + k0 + scol, &As[j * 512]);
      async_cp16(Bt + (bn + row) * K + k0 + scol, &Bs[j * 512]);
    }
    __syncthreads();
    bf16x8 af[4], bfr[4];
#pragma unroll
    for (int mi = 0; mi < 4; ++mi)
      af[mi] = ld8(&As[(wm + mi * 16 + l15) * 32 + quad * 8]);
#pragma unroll
    for (int ni = 0; ni < 4; ++ni)
      bfr[ni] = ld8(&Bs[(wn + ni * 16 + l15) * 32 + quad * 8]);
#pragma unroll
    for (int mi = 0; mi < 4; ++mi)
#pragma unroll
      for (int ni = 0; ni < 4; ++ni)
        acc[mi][ni] = mfma16(af[mi], bfr[ni], acc[mi][ni]);
    __syncthreads();
  }
  // epilogue: C layout col=lane&15, row=quad*4+r (m89-verified)
#pragma unroll
  for (int ni = 0; ni < 4; ++ni) {
    const long col = bn + wn + ni * 16 + l15;
    const float sc = scale[col];
#pragma unroll
    for (int mi = 0; mi < 4; ++mi) {
      const long row0 = bm + wm + mi * 16 + quad * 4;
#pragma unroll
      for (int r = 0; r < 4; ++r) {
        float v = acc[mi][ni][r] * sc;
        if constexpr (OUT_BF16) ((u16*)Cv)[(row0 + r) * (long)N + col] = f2bf(v);
        else                    ((float*)Cv)[(row0 + r) * (long)N + col] = v;
      }
    }
  }
}

// ---------------- l2norm(q,k); fold qk_gain^2*log2e/sqrt(HD) into q ---------
__global__ __launch_bounds__(256) void k_norm_qk(u16* __restrict__ qkv,
                                                 const float* __restrict__ qk_gain) {
  const int token = blockIdx.x;                  // 0..4095
  const int wave = threadIdx.x >> 6, lane = threadIdx.x & 63;
  const float g = qk_gain[0];
  // q' = l2norm(q) * g^2 * log2(e) / sqrt(128); k' = l2norm(k)
  const float qmul = g * g * 1.44269504f * 0.08838834764f;
  u16* rowp = qkv + (long)token * TC3;
#pragma unroll
  for (int s = 0; s < 8; ++s) {
    const int seg = wave * 8 + s;                // 0..31: 16 q-heads, 16 k-heads
    const int isK = seg >> 4;
    const int h = seg & 15;
    u16* ptr = rowp + isK * C_ + h * 128 + lane * 2;
    unsigned pv = *(const unsigned*)ptr;
    float a = bf2f((u16)(pv & 0xffffu));
    float bb = bf2f((u16)(pv >> 16));
    float ss = a * a + bb * bb;
#pragma unroll
    for (int m = 1; m <= 32; m <<= 1) ss += __shfl_xor(ss, m);
    float denom = fmaxf(sqrtf(ss), 1e-12f);
    float f = (isK ? 1.0f : qmul) / denom;
    u16 o0 = f2bf(a * f), o1 = f2bf(bb * f);
    *(unsigned*)ptr = (unsigned)o0 | ((unsigned)o1 << 16);
  }
}

// ---------------- flash attention (causal), exp2 path -----------------------
// block: 64 queries (4 waves x 16), K/V tiles of 64 keys staged in padded LDS.
__global__ __launch_bounds__(256) void k_attn(const u16* __restrict__ qkv,
                                              u16* __restrict__ y) {
  const int qt = 31 - blockIdx.x;          // heavy blocks dispatch first
  const int h  = blockIdx.y;
  const int bz = blockIdx.z;
  const int tid = threadIdx.x, w = tid >> 6, lane = tid & 63;
  const int l15 = lane & 15, quad = lane >> 4;

  __shared__ u16 Ks[64 * 136];             // pad +8: 2-way-free b128 reads
  __shared__ u16 Vs[64 * 132];             // pad +4: conflict-free u16 gathers
  __shared__ u16 Ps[4][16 * 72];           // per-wave P (C->A layout bridge)

  const long tokbase = (long)bz * T_;
  const int qbase = qt * 64 + w * 16;

  // Q fragments (A-layout) held in registers for the whole kernel
  bf16x8 qf[4];
  {
    const u16* qp = qkv + (tokbase + qbase + l15) * TC3 + h * 128 + quad * 8;
#pragma unroll
    for (int kc = 0; kc < 4; ++kc)
      qf[kc] = ld8(qp + kc * 32);
  }

  f32x4 o[8] = {};
  float mrow[4], lrow[4];
#pragma unroll
  for (int r = 0; r < 4; ++r) { mrow[r] = -1e30f; lrow[r] = 0.f; }

  const int srow = tid >> 4;               // 0..15
  const int scol = (tid & 15) * 8;         // elem col (x8 bf16 = 16B)

  for (int kt = 0; kt <= qt; ++kt) {
    const int ktb = kt * 64;
    // --- cooperative K/V staging (padded, reg->LDS) ---
#pragma unroll
    for (int rr = 0; rr < 4; ++rr) {
      const int row = rr * 16 + srow;
      const u16* kgp = qkv + (tokbase + ktb + row) * TC3 + C_ + h * 128 + scol;
      int4 kd = *(const int4*)kgp;
      int4 vd = *(const int4*)(kgp + C_);  // v is +2048 elems after k
      *(int4*)&Ks[row * 136 + scol] = kd;
      *(int2*)&Vs[row * 132 + scol]     = make_int2(vd.x, vd.y);
      *(int2*)&Vs[row * 132 + scol + 4] = make_int2(vd.z, vd.w);
    }
    __syncthreads();

    const int nvalid = min(64, qbase + 16 - ktb);   // keys this wave can see
    const int nkb = (nvalid + 15) >> 4;             // 16-key S blocks
    const int nkc = (nvalid + 31) >> 5;             // 32-key PV chunks
    const bool diag = (kt == qt);

    // --- S = Q K^T (scaled+log2e already folded into q) ---
    f32x4 s[4];
#pragma unroll
    for (int kb = 0; kb < 4; ++kb) {
      if (kb < nkb) {
        f32x4 sb = {0.f, 0.f, 0.f, 0.f};
#pragma unroll
        for (int kc = 0; kc < 4; ++kc) {
          bf16x8 kf = ld8(&Ks[(kb * 16 + l15) * 136 + kc * 32 + quad * 8]);
          sb = mfma16(qf[kc], kf, sb);
        }
        if (diag) {
          const int kgi = ktb + kb * 16 + l15;
#pragma unroll
          for (int r = 0; r < 4; ++r)
            if (kgi > qbase + quad * 4 + r) sb[r] = -1e30f;
        }
        s[kb] = sb;
      }
    }
    // --- online softmax (rows span the 16 lanes of a quad-group) ---
    float alpha[4];
#pragma unroll
    for (int r = 0; r < 4; ++r) {
      float mx = -1e30f;
#pragma unroll
      for (int kb = 0; kb < 4; ++kb)
        if (kb < nkb) mx = fmaxf(mx, s[kb][r]);
      mx = fmaxf(mx, __shfl_xor(mx, 1));
      mx = fmaxf(mx, __shfl_xor(mx, 2));
      mx = fmaxf(mx, __shfl_xor(mx, 4));
      mx = fmaxf(mx, __shfl_xor(mx, 8));
      const float mnew = fmaxf(mrow[r], mx);
      alpha[r] = __builtin_amdgcn_exp2f(mrow[r] - mnew);
      mrow[r] = mnew;
      float rs = 0.f;
#pragma unroll
      for (int kb = 0; kb < 4; ++kb)
        if (kb < nkb) {
          float p = __builtin_amdgcn_exp2f(s[kb][r] - mnew);
          s[kb][r] = p;
          rs += p;
        }
      rs += __shfl_xor(rs, 1); rs += __shfl_xor(rs, 2);
      rs += __shfl_xor(rs, 4); rs += __shfl_xor(rs, 8);
      lrow[r] = lrow[r] * alpha[r] + rs;
    }
#pragma unroll
    for (int db = 0; db < 8; ++db)
#pragma unroll
      for (int r = 0; r < 4; ++r)
        o[db][r] *= alpha[r];
    // --- P: C-layout -> LDS -> A-layout (m120 bridge) ---
    u16* pw = &Ps[w][0];
#pragma unroll
    for (int kb = 0; kb < 4; ++kb) {
      if (kb < nkb) {
#pragma unroll
        for (int r = 0; r < 4; ++r)
          pw[(quad * 4 + r) * 72 + kb * 16 + l15] = f2bf(s[kb][r]);
      } else if (kb < 2 * nkc) {
#pragma unroll
        for (int r = 0; r < 4; ++r)
          pw[(quad * 4 + r) * 72 + kb * 16 + l15] = 0;
      }
    }
    // --- O += P V ---
#pragma unroll
    for (int kc2 = 0; kc2 < 2; ++kc2) {
      if (kc2 < nkc) {
        bf16x8 pa = ld8(&pw[l15 * 72 + kc2 * 32 + quad * 8]);
#pragma unroll
        for (int db = 0; db < 8; ++db) {
          short8 vv;
#pragma unroll
          for (int j = 0; j < 8; ++j)
            vv[j] = (short)Vs[(kc2 * 32 + quad * 8 + j) * 132 + db * 16 + l15];
          o[db] = mfma16(pa, __builtin_bit_cast(bf16x8, vv), o[db]);
        }
      }
    }
    __syncthreads();
  }
  // --- epilogue: y[b, t, h*128+d] = o / l ---
  float inv_l[4];
#pragma unroll
  for (int r = 0; r < 4; ++r) inv_l[r] = 1.0f / lrow[r];
#pragma unroll
  for (int db = 0; db < 8; ++db) {
    const int d = h * 128 + db * 16 + l15;
#pragma unroll
    for (int r = 0; r < 4; ++r) {
      const long t = tokbase + qbase + quad * 4 + r;
      y[t * (long)C_ + d] = f2bf(o[db][r] * inv_l[r]);
    }
  }
}

// ---------------------------------------------------------------------------
extern "C" void kernel_launch(void* const* d_in, const int* in_sizes, int n_in,
                              void* d_out, int out_size, void* d_ws, size_t ws_size,
                              hipStream_t stream) {
  const float* x    = (const float*)d_in[0];
  const int*   aw   = (const int*)d_in[1];
  const float* asc  = (const float*)d_in[2];
  const int*   pw   = (const int*)d_in[3];
  const float* psc  = (const float*)d_in[4];
  const float* gain = (const float*)d_in[5];

  char* ws = (char*)d_ws;
  u16* xb  = (u16*)(ws);                         // 16.78 MB
  u16* wab = (u16*)(ws + 16777216UL);            // 25.17 MB
  u16* wpb = (u16*)(ws + 41943040UL);            //  8.39 MB
  u16* qkv = (u16*)(ws + 50331648UL);            // 50.33 MB
  u16* yb  = (u16*)(ws + 100663296UL);           // 16.78 MB (end 117.4 MB)

  k_cast_x<<<8192, 256, 0, stream>>>(x, xb);
  k_cast_w<<<12288, 256, 0, stream>>>(aw, wab);
  k_cast_w<<<4096, 256, 0, stream>>>(pw, wpb);
  k_gemm_bt<true><<<dim3(48, 32), 256, 0, stream>>>(xb, wab, asc, qkv, TC3, (long)C_);
  k_norm_qk<<<4096, 256, 0, stream>>>(qkv, gain);
  k_attn<<<dim3(32, 16, 2), 256, 0, stream>>>(qkv, yb);
  k_gemm_bt<false><<<dim3(16, 32), 256, 0, stream>>>(yb, wpb, psc, (float*)d_out, C_, (long)C_);
}

// Round 2
// 559.346 us; speedup vs baseline: 1.2322x; 1.2322x over previous
//
#include <hip/hip_runtime.h>

// ---------------------------------------------------------------------------
// QKGainAttention on MI355X (gfx950), round 2.
// Change vs round 1: eliminate the PV V-fragment scalar-gather (128
// ds_read_u16/wave/tile). V is pre-transposed to Vt_g[bz][h][d][t] by k_vt
// (into the dead x_bf16 ws region), staged per-tile into padded LDS rows,
// and PV B-fragments become ds_read_b128.
// Workspace layout (bytes):
//   [0,16M)        x_bf16 4096x2048   -- dead after QKV GEMM; reused as Vt_g
//   [16M,41.9M)    attn_w bf16 6144x2048
//   [41.9M,50.3M)  proj_w bf16 2048x2048
//   [50.3M,100.6M) qkv bf16 4096x6144
//   [100.6M,117.4M) y bf16 4096x2048
// ---------------------------------------------------------------------------

#define DEVINL __device__ __forceinline__

typedef unsigned short u16;
typedef __bf16 bf16x8 __attribute__((ext_vector_type(8)));
typedef float  f32x4  __attribute__((ext_vector_type(4)));
typedef short  short8 __attribute__((ext_vector_type(8)));
typedef u16    u16x4  __attribute__((ext_vector_type(4)));

static constexpr int T_  = 2048;
static constexpr int C_  = 2048;
static constexpr int TC3 = 6144;   // 3*C

DEVINL u16 f2bf(float f) {
  union { float f; unsigned u; } v; v.f = f;
  unsigned r = v.u + 0x7FFFu + ((v.u >> 16) & 1u);   // RNE
  return (u16)(r >> 16);
}
DEVINL float bf2f(u16 s) {
  union { unsigned u; float f; } v; v.u = ((unsigned)s) << 16;
  return v.f;
}
DEVINL bf16x8 ld8(const u16* p) {
  return __builtin_bit_cast(bf16x8, *(const short8*)p);
}
DEVINL f32x4 mfma16(bf16x8 a, bf16x8 b, f32x4 c) {
  return __builtin_amdgcn_mfma_f32_16x16x32_bf16(a, b, c, 0, 0, 0);
}
DEVINL void async_cp16(const u16* gp, u16* lp) {
  __builtin_amdgcn_global_load_lds(
      (const __attribute__((address_space(1))) void*)gp,
      (__attribute__((address_space(3))) void*)lp, 16, 0, 0);
}

// ---------------- dtype casts ----------------
__global__ __launch_bounds__(256) void k_cast_x(const float* __restrict__ in,
                                                u16* __restrict__ out) {
  long i = (long)(blockIdx.x * 256 + threadIdx.x) * 4;
  float4 v = *(const float4*)(in + i);
  u16x4 o; o.x = f2bf(v.x); o.y = f2bf(v.y); o.z = f2bf(v.z); o.w = f2bf(v.w);
  *(u16x4*)(out + i) = o;
}
__global__ __launch_bounds__(256) void k_cast_w(const int* __restrict__ in,
                                                u16* __restrict__ out) {
  long i = (long)(blockIdx.x * 256 + threadIdx.x) * 4;
  int4 v = *(const int4*)(in + i);
  u16x4 o; o.x = f2bf((float)v.x); o.y = f2bf((float)v.y);
  o.z = f2bf((float)v.z); o.w = f2bf((float)v.w);
  *(u16x4*)(out + i) = o;
}

// ---------------- GEMM: C[m,n] = (sum_k A[m,k]*Bt[n,k]) * scale[n] ----------
template<bool OUT_BF16>
__global__ __launch_bounds__(256) void k_gemm_bt(
    const u16* __restrict__ A, const u16* __restrict__ Bt,
    const float* __restrict__ scale, void* __restrict__ Cv,
    int N, long K) {
  __shared__ u16 As[128 * 32];
  __shared__ u16 Bs[128 * 32];
  const int tid  = threadIdx.x;
  const int wave = tid >> 6;
  const int lane = tid & 63;
  const int l15  = lane & 15;
  const int quad = lane >> 4;
  const int wm = (wave & 1) * 64;
  const int wn = (wave >> 1) * 64;
  const long bm = (long)blockIdx.y * 128;
  const long bn = (long)blockIdx.x * 128;

  f32x4 acc[4][4] = {};

  const int srow = lane >> 2;
  const int scol = (lane & 3) * 8;

  for (long k0 = 0; k0 < K; k0 += 32) {
#pragma unroll
    for (int i = 0; i < 2; ++i) {
      const int j = wave * 2 + i;
      const int row = j * 16 + srow;
      async_cp16(A  + (bm + row) * K + k0 + scol, &As[j * 512]);
      async_cp16(Bt + (bn + row) * K + k0 + scol, &Bs[j * 512]);
    }
    __syncthreads();
    bf16x8 af[4], bfr[4];
#pragma unroll
    for (int mi = 0; mi < 4; ++mi)
      af[mi] = ld8(&As[(wm + mi * 16 + l15) * 32 + quad * 8]);
#pragma unroll
    for (int ni = 0; ni < 4; ++ni)
      bfr[ni] = ld8(&Bs[(wn + ni * 16 + l15) * 32 + quad * 8]);
#pragma unroll
    for (int mi = 0; mi < 4; ++mi)
#pragma unroll
      for (int ni = 0; ni < 4; ++ni)
        acc[mi][ni] = mfma16(af[mi], bfr[ni], acc[mi][ni]);
    __syncthreads();
  }
#pragma unroll
  for (int ni = 0; ni < 4; ++ni) {
    const long col = bn + wn + ni * 16 + l15;
    const float sc = scale[col];
#pragma unroll
    for (int mi = 0; mi < 4; ++mi) {
      const long row0 = bm + wm + mi * 16 + quad * 4;
#pragma unroll
      for (int r = 0; r < 4; ++r) {
        float v = acc[mi][ni][r] * sc;
        if constexpr (OUT_BF16) ((u16*)Cv)[(row0 + r) * (long)N + col] = f2bf(v);
        else                    ((float*)Cv)[(row0 + r) * (long)N + col] = v;
      }
    }
  }
}

// ---------------- l2norm(q,k); fold qk_gain^2*log2e/sqrt(HD) into q ---------
__global__ __launch_bounds__(256) void k_norm_qk(u16* __restrict__ qkv,
                                                 const float* __restrict__ qk_gain) {
  const int token = blockIdx.x;
  const int wave = threadIdx.x >> 6, lane = threadIdx.x & 63;
  const float g = qk_gain[0];
  const float qmul = g * g * 1.44269504f * 0.08838834764f;
  u16* rowp = qkv + (long)token * TC3;
#pragma unroll
  for (int s = 0; s < 8; ++s) {
    const int seg = wave * 8 + s;
    const int isK = seg >> 4;
    const int h = seg & 15;
    u16* ptr = rowp + isK * C_ + h * 128 + lane * 2;
    unsigned pv = *(const unsigned*)ptr;
    float a = bf2f((u16)(pv & 0xffffu));
    float bb = bf2f((u16)(pv >> 16));
    float ss = a * a + bb * bb;
#pragma unroll
    for (int m = 1; m <= 32; m <<= 1) ss += __shfl_xor(ss, m);
    float denom = fmaxf(sqrtf(ss), 1e-12f);
    float f = (isK ? 1.0f : qmul) / denom;
    u16 o0 = f2bf(a * f), o1 = f2bf(bb * f);
    *(unsigned*)ptr = (unsigned)o0 | ((unsigned)o1 << 16);
  }
}

// ---------------- V transpose: qkv V block -> Vt_g[bz][h][d][t] -------------
// Scattered 2B reads are L1-absorbed (256 lines/block, reused 8x each);
// writes are lane-contiguous 128B segments. ~17 MB R+W total.
__global__ __launch_bounds__(256) void k_vt(const u16* __restrict__ qkv,
                                            u16* __restrict__ vt) {
  const int t0 = blockIdx.x * 64;
  const int h = blockIdx.y, bz = blockIdx.z;
  const int t = threadIdx.x & 63;
  const int d0 = threadIdx.x >> 6;         // 0..3
  const long tokbase = (long)bz * T_;
  const u16* src = qkv + (tokbase + t0 + t) * (long)TC3 + 2 * C_ + h * 128;
  u16* dst = vt + ((long)(bz * 16 + h) * 128) * (long)T_ + t0 + t;
#pragma unroll
  for (int dd = 0; dd < 32; ++dd) {
    const int d = dd * 4 + d0;
    dst[(long)d * T_] = src[d];
  }
}

// ---------------- flash attention (causal), exp2 path -----------------------
__global__ __launch_bounds__(256) void k_attn(const u16* __restrict__ qkv,
                                              const u16* __restrict__ vtg,
                                              u16* __restrict__ y) {
  const int qt = 31 - blockIdx.x;          // heavy blocks dispatch first
  const int h  = blockIdx.y;
  const int bz = blockIdx.z;
  const int tid = threadIdx.x, w = tid >> 6, lane = tid & 63;
  const int l15 = lane & 15, quad = lane >> 4;

  __shared__ u16 Ks[64 * 136];             // pad +8: 2-way-free b128 reads
  __shared__ u16 Vt[128 * 72];             // V^T tile: [d][k], pad to 72
  __shared__ u16 Ps[4][16 * 72];           // per-wave P (C->A layout bridge)

  const long tokbase = (long)bz * T_;
  const int qbase = qt * 64 + w * 16;
  const u16* vbase = vtg + ((long)(bz * 16 + h) * 128) * (long)T_;

  // Q fragments (A-layout) held in registers for the whole kernel
  bf16x8 qf[4];
  {
    const u16* qp = qkv + (tokbase + qbase + l15) * TC3 + h * 128 + quad * 8;
#pragma unroll
    for (int kc = 0; kc < 4; ++kc)
      qf[kc] = ld8(qp + kc * 32);
  }

  f32x4 o[8] = {};
  float mrow[4], lrow[4];
#pragma unroll
  for (int r = 0; r < 4; ++r) { mrow[r] = -1e30f; lrow[r] = 0.f; }

  const int srow = tid >> 4;               // K staging: row 0..15
  const int scol = (tid & 15) * 8;
  const int vds  = tid >> 3;               // Vt staging: d within 32-group
  const int vko  = (tid & 7) * 8;          // k offset (x8 u16 = 16B)

  for (int kt = 0; kt <= qt; ++kt) {
    const int ktb = kt * 64;
    // --- K staging: [k][d] rows, padded ---
#pragma unroll
    for (int rr = 0; rr < 4; ++rr) {
      const int row = rr * 16 + srow;
      int4 kd = *(const int4*)(qkv + (tokbase + ktb + row) * TC3 + C_ + h * 128 + scol);
      *(int4*)&Ks[row * 136 + scol] = kd;
    }
    // --- Vt staging: [d][k] rows from pre-transposed global ---
#pragma unroll
    for (int ii = 0; ii < 4; ++ii) {
      const int d = ii * 32 + vds;
      int4 vv = *(const int4*)(vbase + (long)d * T_ + ktb + vko);
      *(int4*)&Vt[d * 72 + vko] = vv;
    }
    __syncthreads();

    const int nvalid = min(64, qbase + 16 - ktb);
    const int nkb = (nvalid + 15) >> 4;
    const int nkc = (nvalid + 31) >> 5;
    const bool diag = (kt == qt);

    // --- S = Q K^T (scale+log2e folded into q) ---
    f32x4 s[4];
#pragma unroll
    for (int kb = 0; kb < 4; ++kb) {
      if (kb < nkb) {
        f32x4 sb = {0.f, 0.f, 0.f, 0.f};
#pragma unroll
        for (int kc = 0; kc < 4; ++kc) {
          bf16x8 kf = ld8(&Ks[(kb * 16 + l15) * 136 + kc * 32 + quad * 8]);
          sb = mfma16(qf[kc], kf, sb);
        }
        if (diag) {
          const int kgi = ktb + kb * 16 + l15;
#pragma unroll
          for (int r = 0; r < 4; ++r)
            if (kgi > qbase + quad * 4 + r) sb[r] = -1e30f;
        }
        s[kb] = sb;
      }
    }
    // --- online softmax (rows span the 16 lanes of a quad-group) ---
    float alpha[4];
#pragma unroll
    for (int r = 0; r < 4; ++r) {
      float mx = -1e30f;
#pragma unroll
      for (int kb = 0; kb < 4; ++kb)
        if (kb < nkb) mx = fmaxf(mx, s[kb][r]);
      mx = fmaxf(mx, __shfl_xor(mx, 1));
      mx = fmaxf(mx, __shfl_xor(mx, 2));
      mx = fmaxf(mx, __shfl_xor(mx, 4));
      mx = fmaxf(mx, __shfl_xor(mx, 8));
      const float mnew = fmaxf(mrow[r], mx);
      alpha[r] = __builtin_amdgcn_exp2f(mrow[r] - mnew);
      mrow[r] = mnew;
      float rs = 0.f;
#pragma unroll
      for (int kb = 0; kb < 4; ++kb)
        if (kb < nkb) {
          float p = __builtin_amdgcn_exp2f(s[kb][r] - mnew);
          s[kb][r] = p;
          rs += p;
        }
      rs += __shfl_xor(rs, 1); rs += __shfl_xor(rs, 2);
      rs += __shfl_xor(rs, 4); rs += __shfl_xor(rs, 8);
      lrow[r] = lrow[r] * alpha[r] + rs;
    }
#pragma unroll
    for (int db = 0; db < 8; ++db)
#pragma unroll
      for (int r = 0; r < 4; ++r)
        o[db][r] *= alpha[r];
    // --- P: C-layout -> LDS -> A-layout (m120 bridge) ---
    u16* pw = &Ps[w][0];
#pragma unroll
    for (int kb = 0; kb < 4; ++kb) {
      if (kb < nkb) {
#pragma unroll
        for (int r = 0; r < 4; ++r)
          pw[(quad * 4 + r) * 72 + kb * 16 + l15] = f2bf(s[kb][r]);
      } else if (kb < 2 * nkc) {
#pragma unroll
        for (int r = 0; r < 4; ++r)
          pw[(quad * 4 + r) * 72 + kb * 16 + l15] = 0;
      }
    }
    // --- O += P V : both fragments now ds_read_b128 ---
#pragma unroll
    for (int kc2 = 0; kc2 < 2; ++kc2) {
      if (kc2 < nkc) {
        bf16x8 pa = ld8(&pw[l15 * 72 + kc2 * 32 + quad * 8]);
#pragma unroll
        for (int db = 0; db < 8; ++db) {
          bf16x8 vf = ld8(&Vt[(db * 16 + l15) * 72 + kc2 * 32 + quad * 8]);
          o[db] = mfma16(pa, vf, o[db]);
        }
      }
    }
    __syncthreads();
  }
  // --- epilogue: y[b, t, h*128+d] = o / l ---
  float inv_l[4];
#pragma unroll
  for (int r = 0; r < 4; ++r) inv_l[r] = 1.0f / lrow[r];
#pragma unroll
  for (int db = 0; db < 8; ++db) {
    const int d = h * 128 + db * 16 + l15;
#pragma unroll
    for (int r = 0; r < 4; ++r) {
      const long t = tokbase + qbase + quad * 4 + r;
      y[t * (long)C_ + d] = f2bf(o[db][r] * inv_l[r]);
    }
  }
}

// ---------------------------------------------------------------------------
extern "C" void kernel_launch(void* const* d_in, const int* in_sizes, int n_in,
                              void* d_out, int out_size, void* d_ws, size_t ws_size,
                              hipStream_t stream) {
  const float* x    = (const float*)d_in[0];
  const int*   aw   = (const int*)d_in[1];
  const float* asc  = (const float*)d_in[2];
  const int*   pw   = (const int*)d_in[3];
  const float* psc  = (const float*)d_in[4];
  const float* gain = (const float*)d_in[5];

  char* ws = (char*)d_ws;
  u16* xb  = (u16*)(ws);                         // 16.78 MB (reused as Vt_g)
  u16* wab = (u16*)(ws + 16777216UL);
  u16* wpb = (u16*)(ws + 41943040UL);
  u16* qkv = (u16*)(ws + 50331648UL);
  u16* yb  = (u16*)(ws + 100663296UL);
  u16* vtg = xb;                                 // x_bf16 dead after QKV GEMM

  k_cast_x<<<8192, 256, 0, stream>>>(x, xb);
  k_cast_w<<<12288, 256, 0, stream>>>(aw, wab);
  k_cast_w<<<4096, 256, 0, stream>>>(pw, wpb);
  k_gemm_bt<true><<<dim3(48, 32), 256, 0, stream>>>(xb, wab, asc, qkv, TC3, (long)C_);
  k_norm_qk<<<4096, 256, 0, stream>>>(qkv, gain);
  k_vt<<<dim3(32, 16, 2), 256, 0, stream>>>(qkv, vtg);
  k_attn<<<dim3(32, 16, 2), 256, 0, stream>>>(qkv, vtg, yb);
  k_gemm_bt<false><<<dim3(16, 32), 256, 0, stream>>>(yb, wpb, psc, (float*)d_out, C_, (long)C_);
}